// Round 1
// baseline (196.371 us; speedup 1.0000x reference)
//
#include <hip/hip_runtime.h>
#include <hip/hip_bf16.h>
#include <math.h>

// Problem constants
#define L_SEQ   1024
#define NB      8
#define H_DIM   300
#define KWIN    5
#define NREL    11          // 2K+1
#define PDIM    50
#define NC      11234       // band pair count for L=1024, K=5
#define BNC     (NB*NC)     // 89872
#define LN_EPS  1e-5f

// Workspace layout (floats)
#define PREL_OFF 0                       // 11*300 -> padded 4096
#define AE_OFF   4096                    // 8192*300
#define AC_OFF   (4096 + 8192*300)       // 8192*300
// total = 4096 + 2*2457600 = 4,919,296 floats = 19.7 MB

// ---------------------------------------------------------------------------
// n -> (i, j) for the band, row-major (i outer). Verified against the numpy
// _band_indices ordering:
//   i<5   : starts 0,6,13,21,30  (j from 0)
//   5..1018: start 40 + (i-5)*11, j = i-5 + t%11
//   i>=1019: starts 11194,11204,11213,11221,11228 (j from i-5)
__device__ __forceinline__ void pair_from_n(int n, int& i, int& j) {
    if (n < 40) {
        if      (n < 6)  { i = 0; j = n; }
        else if (n < 13) { i = 1; j = n - 6; }
        else if (n < 21) { i = 2; j = n - 13; }
        else if (n < 30) { i = 3; j = n - 21; }
        else             { i = 4; j = n - 30; }
    } else if (n < 11194) {
        int t = n - 40;
        i = 5 + t / 11;
        j = (i - 5) + t % 11;
    } else {
        if      (n < 11204) { i = 1019; j = 1014 + (n - 11194); }
        else if (n < 11213) { i = 1020; j = 1015 + (n - 11204); }
        else if (n < 11221) { i = 1021; j = 1016 + (n - 11213); }
        else if (n < 11228) { i = 1022; j = 1017 + (n - 11221); }
        else                { i = 1023; j = 1018 + (n - 11228); }
    }
}

// ---------------------------------------------------------------------------
// Kernel 1: prel[r][h] = b1[h] + sum_d W1[h][600+d] * emb11[r][d]
// emb11[r][d] = sum_{r2} (1024-|r2-5|) * exp(-(r-r2)^2) * pos_W[r2][d]
__global__ __launch_bounds__(256) void prep_kernel(
    const float* __restrict__ pos_W, const float* __restrict__ W1,
    const float* __restrict__ b1, float* __restrict__ prel)
{
    __shared__ float semb[NREL * PDIM];  // 550 floats
    for (int t = threadIdx.x; t < NREL * PDIM; t += 256) {
        int r = t / PDIM, d = t % PDIM;
        float acc = 0.f;
#pragma unroll
        for (int r2 = 0; r2 < NREL; ++r2) {
            float cnt = (float)(L_SEQ - abs(r2 - KWIN));
            int dr = r - r2;
            acc += cnt * expf(-(float)(dr * dr)) * pos_W[r2 * PDIM + d];
        }
        semb[t] = acc;
    }
    __syncthreads();
    for (int t = threadIdx.x; t < NREL * H_DIM; t += 256) {
        int r = t / H_DIM, h = t % H_DIM;
        float acc = b1[h];
        const float* wrow = W1 + (size_t)h * 650 + 600;
        const float* em = semb + r * PDIM;
#pragma unroll 10
        for (int d = 0; d < PDIM; ++d) acc += wrow[d] * em[d];
        prel[t] = acc;
    }
}

// ---------------------------------------------------------------------------
// Kernel 2: dual GEMM.
//   z=0: Ae[m][n] = sum_k (h_e[m][k]+h_share[m][k]) * W1[n][k]
//   z=1: Ac[m][n] = sum_k (h_c[m][k]+h_share[m][k]) * W1[n][300+k]
// M = 8192, N = 300, K = 300. Classic 64x64 tile, BK=16, 4x4 per thread.
#define GM 64
#define GN 64
#define GK 16
#define LDT 68   // LDS row stride in floats: 68*4B = 272B, 16B-aligned rows

__global__ __launch_bounds__(256) void dual_gemm(
    const float* __restrict__ h_e, const float* __restrict__ h_c,
    const float* __restrict__ h_share, const float* __restrict__ W1,
    float* __restrict__ Ae, float* __restrict__ Ac)
{
    __shared__ __align__(16) float As[GK * LDT];
    __shared__ __align__(16) float Bs[GK * LDT];

    const int m0 = blockIdx.x * GM;
    const int n0 = blockIdx.y * GN;
    const int z  = blockIdx.z;
    const float* X1  = z ? h_c : h_e;
    const int   woff = z ? H_DIM : 0;
    float* C = z ? Ac : Ae;

    const int tid  = threadIdx.x;
    const int arow = tid >> 2;         // 0..63
    const int ac4  = (tid & 3) * 4;    // 0,4,8,12
    const int tn = tid & 15;
    const int tm = tid >> 4;

    float acc[4][4] = {};

    for (int k0 = 0; k0 < H_DIM; k0 += GK) {
        // ---- stage A tile (64 rows x 16 k), X = X1 + h_share
        {
            int k = k0 + ac4;
            float4 va = make_float4(0.f, 0.f, 0.f, 0.f);
            if (k < H_DIM) {   // K=300 multiple of 4, so full float4 in range
                const size_t row = (size_t)(m0 + arow) * H_DIM + k;
                float4 a = *(const float4*)(X1 + row);
                float4 b = *(const float4*)(h_share + row);
                va = make_float4(a.x + b.x, a.y + b.y, a.z + b.z, a.w + b.w);
            }
            As[(ac4 + 0) * LDT + arow] = va.x;
            As[(ac4 + 1) * LDT + arow] = va.y;
            As[(ac4 + 2) * LDT + arow] = va.z;
            As[(ac4 + 3) * LDT + arow] = va.w;

            // ---- stage W tile (64 n-rows x 16 k); W1 row stride 650 (8B align)
            float4 vb = make_float4(0.f, 0.f, 0.f, 0.f);
            int n = n0 + arow;
            if (n < H_DIM && k < H_DIM) {
                const float* pw = W1 + (size_t)n * 650 + woff + k;
                float2 w0 = *(const float2*)pw;
                float2 w1 = *(const float2*)(pw + 2);
                vb = make_float4(w0.x, w0.y, w1.x, w1.y);
            }
            Bs[(ac4 + 0) * LDT + arow] = vb.x;
            Bs[(ac4 + 1) * LDT + arow] = vb.y;
            Bs[(ac4 + 2) * LDT + arow] = vb.z;
            Bs[(ac4 + 3) * LDT + arow] = vb.w;
        }
        __syncthreads();
#pragma unroll
        for (int kk = 0; kk < GK; ++kk) {
            float4 a = *(const float4*)&As[kk * LDT + tm * 4];
            float4 b = *(const float4*)&Bs[kk * LDT + tn * 4];
            acc[0][0] += a.x * b.x; acc[0][1] += a.x * b.y; acc[0][2] += a.x * b.z; acc[0][3] += a.x * b.w;
            acc[1][0] += a.y * b.x; acc[1][1] += a.y * b.y; acc[1][2] += a.y * b.z; acc[1][3] += a.y * b.w;
            acc[2][0] += a.z * b.x; acc[2][1] += a.z * b.y; acc[2][2] += a.z * b.z; acc[2][3] += a.z * b.w;
            acc[3][0] += a.w * b.x; acc[3][1] += a.w * b.y; acc[3][2] += a.w * b.z; acc[3][3] += a.w * b.w;
        }
        __syncthreads();
    }

    // ---- store: float4 along n (coalesced across tn)
    const int ncol = n0 + tn * 4;
    if (ncol < H_DIM) {   // N=300 mult of 4 -> full float4 valid when ncol<300
#pragma unroll
        for (int r = 0; r < 4; ++r) {
            int m = m0 + tm * 4 + r;
            *(float4*)&C[(size_t)m * H_DIM + ncol] =
                make_float4(acc[r][0], acc[r][1], acc[r][2], acc[r][3]);
        }
    }
}

// ---------------------------------------------------------------------------
// Kernel 3: epilogue. One wave (64 lanes) per (b, n) pair.
//   h = Ae[b,i] + Ac[b,j] + prel[rel]; LayerNorm; ELU; dot W2; + b2.
// Also writes emo_cau_pos (as float) for b==0 pairs.
__global__ __launch_bounds__(256) void epilogue_kernel(
    const float* __restrict__ Ae, const float* __restrict__ Ac,
    const float* __restrict__ prel,
    const float* __restrict__ ln_g, const float* __restrict__ ln_b,
    const float* __restrict__ W2, const float* __restrict__ b2,
    float* __restrict__ out, float* __restrict__ posout)
{
    const int wave = threadIdx.x >> 6;
    const int lane = threadIdx.x & 63;
    const unsigned p = blockIdx.x * 4 + wave;   // pair id in [0, BNC)
    if (p >= BNC) return;

    const unsigned b = p / NC;
    const int n = (int)(p % NC);
    int i, j;
    pair_from_n(n, i, j);
    const int r = j - i + KWIN;

    const float* ae = Ae + ((size_t)b * L_SEQ + i) * H_DIM;
    const float* ac = Ac + ((size_t)b * L_SEQ + j) * H_DIM;
    const float* pr = prel + (size_t)r * H_DIM;

    float hv[5];
    float s = 0.f, ss = 0.f;
#pragma unroll
    for (int q = 0; q < 5; ++q) {
        int idx = lane + 64 * q;
        float v = 0.f;
        if (idx < H_DIM) v = ae[idx] + ac[idx] + pr[idx];
        hv[q] = v;
        s += v; ss += v * v;
    }
#pragma unroll
    for (int off = 32; off > 0; off >>= 1) {
        s  += __shfl_xor(s, off);
        ss += __shfl_xor(ss, off);
    }
    const float mu   = s * (1.f / H_DIM);
    const float var  = ss * (1.f / H_DIM) - mu * mu;
    const float rsig = rsqrtf(var + LN_EPS);

    float acc = 0.f;
#pragma unroll
    for (int q = 0; q < 5; ++q) {
        int idx = lane + 64 * q;
        if (idx < H_DIM) {
            float g = (hv[q] - mu) * rsig * ln_g[idx] + ln_b[idx];
            g = g > 0.f ? g : expm1f(g);           // ELU, alpha=1
            acc += g * W2[idx];
        }
    }
#pragma unroll
    for (int off = 32; off > 0; off >>= 1) acc += __shfl_xor(acc, off);

    if (lane == 0) {
        out[p] = acc + b2[0];
        if (p < NC) {   // b == 0: write emo_cau_pos once
            posout[2 * (size_t)n]     = (float)(i + 1);
            posout[2 * (size_t)n + 1] = (float)(j + 1);
        }
    }
}

// ---------------------------------------------------------------------------
extern "C" void kernel_launch(void* const* d_in, const int* in_sizes, int n_in,
                              void* d_out, int out_size, void* d_ws, size_t ws_size,
                              hipStream_t stream) {
    const float* h_e     = (const float*)d_in[0];
    const float* h_c     = (const float*)d_in[1];
    const float* h_share = (const float*)d_in[2];
    // d_in[3] = mask (unused)
    const float* pos_W   = (const float*)d_in[4];
    const float* W1      = (const float*)d_in[5];
    const float* b1      = (const float*)d_in[6];
    const float* ln_g    = (const float*)d_in[7];
    const float* ln_b    = (const float*)d_in[8];
    const float* W2      = (const float*)d_in[9];
    const float* b2      = (const float*)d_in[10];

    float* ws   = (float*)d_ws;
    float* prel = ws + PREL_OFF;
    float* Ae   = ws + AE_OFF;
    float* Ac   = ws + AC_OFF;

    float* out    = (float*)d_out;
    float* posout = out + BNC;

    prep_kernel<<<1, 256, 0, stream>>>(pos_W, W1, b1, prel);

    dim3 ggrid(NB * L_SEQ / GM, (H_DIM + GN - 1) / GN, 2);  // 128 x 5 x 2
    dual_gemm<<<ggrid, 256, 0, stream>>>(h_e, h_c, h_share, W1, Ae, Ac);

    epilogue_kernel<<<BNC / 4, 256, 0, stream>>>(Ae, Ac, prel, ln_g, ln_b,
                                                 W2, b2, out, posout);
}

// Round 2
// 183.982 us; speedup vs baseline: 1.0673x; 1.0673x over previous
//
#include <hip/hip_runtime.h>
#include <hip/hip_bf16.h>
#include <math.h>

// Problem constants
#define L_SEQ   1024
#define NB      8
#define H_DIM   300
#define KWIN    5
#define NREL    11          // 2K+1
#define PDIM    50
#define NC      11234       // band pair count for L=1024, K=5
#define BNC     (NB*NC)     // 89872
#define LN_EPS  1e-5f

// Workspace layout (floats)
#define PREL_OFF 0                       // 11*300 -> padded 4096
#define AE_OFF   4096                    // 8192*300
#define AC_OFF   (4096 + 8192*300)       // 8192*300

typedef __attribute__((ext_vector_type(8))) short short8;
typedef __attribute__((ext_vector_type(4))) float f32x4;

// fp32 -> bf16 with round-to-nearest-even
__device__ __forceinline__ short f2bf(float f) {
    unsigned u = __float_as_uint(f);
    u += 0x7fffu + ((u >> 16) & 1u);
    return (short)(u >> 16);
}

// ---------------------------------------------------------------------------
// n -> (i, j) for the band, row-major (i outer). Matches numpy _band_indices.
__device__ __forceinline__ void pair_from_n(int n, int& i, int& j) {
    if (n < 40) {
        if      (n < 6)  { i = 0; j = n; }
        else if (n < 13) { i = 1; j = n - 6; }
        else if (n < 21) { i = 2; j = n - 13; }
        else if (n < 30) { i = 3; j = n - 21; }
        else             { i = 4; j = n - 30; }
    } else if (n < 11194) {
        int t = n - 40;
        i = 5 + t / 11;
        j = (i - 5) + t % 11;
    } else {
        if      (n < 11204) { i = 1019; j = 1014 + (n - 11194); }
        else if (n < 11213) { i = 1020; j = 1015 + (n - 11204); }
        else if (n < 11221) { i = 1021; j = 1016 + (n - 11213); }
        else if (n < 11228) { i = 1022; j = 1017 + (n - 11221); }
        else                { i = 1023; j = 1018 + (n - 11228); }
    }
}

// ---------------------------------------------------------------------------
// Kernel 1: prel[r][h] = b1[h] + sum_d W1[h][600+d] * emb11[r][d]
// emb11[r][d] = sum_{r2} (1024-|r2-5|) * exp(-(r-r2)^2) * pos_W[r2][d]
// Grid: 13 blocks x 256 (was 1 block -> serial on one CU).
__global__ __launch_bounds__(256) void prep_kernel(
    const float* __restrict__ pos_W, const float* __restrict__ W1,
    const float* __restrict__ b1, float* __restrict__ prel)
{
    __shared__ float semb[NREL * PDIM];  // 550 floats, recomputed per block
    for (int t = threadIdx.x; t < NREL * PDIM; t += 256) {
        int r = t / PDIM, d = t % PDIM;
        float acc = 0.f;
#pragma unroll
        for (int r2 = 0; r2 < NREL; ++r2) {
            float cnt = (float)(L_SEQ - abs(r2 - KWIN));
            int dr = r - r2;
            acc += cnt * expf(-(float)(dr * dr)) * pos_W[r2 * PDIM + d];
        }
        semb[t] = acc;
    }
    __syncthreads();
    int t = blockIdx.x * 256 + threadIdx.x;
    if (t < NREL * H_DIM) {
        int r = t / H_DIM, h = t % H_DIM;
        float acc = b1[h];
        const float* wrow = W1 + (size_t)h * 650 + 600;
        const float* em = semb + r * PDIM;
#pragma unroll 10
        for (int d = 0; d < PDIM; ++d) acc += wrow[d] * em[d];
        prel[t] = acc;
    }
}

// ---------------------------------------------------------------------------
// Kernel 2: dual GEMM, bf16 MFMA 16x16x32.
//   z=0: Ae[m][n] = sum_k (h_e[m][k]+h_share[m][k]) * W1[n][k]
//   z=1: Ac[m][n] = sum_k (h_c[m][k]+h_share[m][k]) * W1[n][300+k]
// M=8192, N=300 (5 tiles of 64), K=300 (10 steps of 32, zero-padded).
// Block 256 = 4 waves; tile BM=128 x BN=64; wave = 64x32 = 4x2 mfma frags.
#define BM 128
#define BN 64
#define BK 32

__global__ __launch_bounds__(256) void dual_gemm(
    const float* __restrict__ h_e, const float* __restrict__ h_c,
    const float* __restrict__ h_share, const float* __restrict__ W1,
    float* __restrict__ Ae, float* __restrict__ Ac)
{
    __shared__ __align__(16) short As[BM * BK];   // 8 KB
    __shared__ __align__(16) short Bs[BN * BK];   // 4 KB

    const int m0 = blockIdx.x * BM;
    const int n0 = blockIdx.y * BN;
    const int z  = blockIdx.z;
    const float* X1  = z ? h_c : h_e;
    const int   woff = z ? H_DIM : 0;
    float* C = z ? Ac : Ae;

    const int tid  = threadIdx.x;
    const int wave = tid >> 6;
    const int lane = tid & 63;
    const int wm = (wave & 1) * 64;   // wave m-offset within tile
    const int wn = (wave >> 1) * 32;  // wave n-offset within tile
    const int fr = lane & 15;         // fragment row/col index
    const int fq = lane >> 4;         // quad (k-chunk of 8)

    // A staging map: thread -> (row r = tid>>1, 16 k's at kq=(tid&1)*16)
    const int ar = tid >> 1;
    const int akq = (tid & 1) * 16;
    const size_t arow = (size_t)(m0 + ar) * H_DIM;
    // B staging map: thread -> (n-row tid>>2, 8 k's at (tid&3)*8)
    const int bn = tid >> 2;
    const int bkq = (tid & 3) * 8;
    const bool bvalid = (n0 + bn) < H_DIM;
    const float* brow = W1 + (size_t)(n0 + bn) * 650 + woff;

    f32x4 acc[4][2] = {};

    for (int k0 = 0; k0 < 320; k0 += BK) {
        // ---- stage A: (X1 + h_share) -> bf16, rows m0..m0+127, k0..k0+31
        short av[16];
#pragma unroll
        for (int c = 0; c < 4; ++c) {
            int k = k0 + akq + c * 4;
            float x0 = 0.f, x1 = 0.f, x2 = 0.f, x3 = 0.f;
            if (k < H_DIM) {
                float4 u = *(const float4*)(X1 + arow + k);
                float4 v = *(const float4*)(h_share + arow + k);
                x0 = u.x + v.x; x1 = u.y + v.y; x2 = u.z + v.z; x3 = u.w + v.w;
            }
            av[c*4+0] = f2bf(x0); av[c*4+1] = f2bf(x1);
            av[c*4+2] = f2bf(x2); av[c*4+3] = f2bf(x3);
        }
        *(short8*)&As[ar * BK + akq]     = *(short8*)&av[0];
        *(short8*)&As[ar * BK + akq + 8] = *(short8*)&av[8];

        // ---- stage B: W1 rows n0..n0+63 -> bf16 (float2 loads: stride 650)
        short bv[8] = {0,0,0,0,0,0,0,0};
#pragma unroll
        for (int c = 0; c < 4; ++c) {
            int k = k0 + bkq + c * 2;
            if (bvalid && k < H_DIM) {
                float2 w = *(const float2*)(brow + k);
                bv[c*2]   = f2bf(w.x);
                bv[c*2+1] = f2bf(w.y);
            }
        }
        *(short8*)&Bs[bn * BK + bkq] = *(short8*)&bv[0];

        __syncthreads();

        // ---- MFMA: wave computes 64x32 via 4x2 16x16 frags
        short8 af[4], bfr[2];
#pragma unroll
        for (int mt = 0; mt < 4; ++mt)
            af[mt] = *(const short8*)&As[(wm + mt * 16 + fr) * BK + fq * 8];
#pragma unroll
        for (int nt = 0; nt < 2; ++nt)
            bfr[nt] = *(const short8*)&Bs[(wn + nt * 16 + fr) * BK + fq * 8];
#pragma unroll
        for (int mt = 0; mt < 4; ++mt)
#pragma unroll
            for (int nt = 0; nt < 2; ++nt)
                acc[mt][nt] = __builtin_amdgcn_mfma_f32_16x16x32_bf16(
                    af[mt], bfr[nt], acc[mt][nt], 0, 0, 0);

        __syncthreads();
    }

    // ---- store: C/D layout col=lane&15, row=quad*4+reg
#pragma unroll
    for (int nt = 0; nt < 2; ++nt) {
        const int col = n0 + wn + nt * 16 + fr;
        if (col < H_DIM) {
#pragma unroll
            for (int mt = 0; mt < 4; ++mt) {
                const int rbase = m0 + wm + mt * 16 + fq * 4;
#pragma unroll
                for (int r2 = 0; r2 < 4; ++r2)
                    C[(size_t)(rbase + r2) * H_DIM + col] = acc[mt][nt][r2];
            }
        }
    }
}

// ---------------------------------------------------------------------------
// Kernel 3: epilogue. One wave per (b, n) pair. float4 loads:
//   lanes 0..63 cover floats 0..255; lanes 0..10 cover 256..299.
__global__ __launch_bounds__(256) void epilogue_kernel(
    const float* __restrict__ Ae, const float* __restrict__ Ac,
    const float* __restrict__ prel,
    const float* __restrict__ ln_g, const float* __restrict__ ln_b,
    const float* __restrict__ W2, const float* __restrict__ b2,
    float* __restrict__ out, float* __restrict__ posout)
{
    const int wave = threadIdx.x >> 6;
    const int lane = threadIdx.x & 63;
    const unsigned p = blockIdx.x * 4 + wave;   // pair id in [0, BNC)
    if (p >= BNC) return;

    const unsigned b = p / NC;
    const int n = (int)(p % NC);
    int i, j;
    pair_from_n(n, i, j);
    const int r = j - i + KWIN;

    const float* ae = Ae + ((size_t)b * L_SEQ + i) * H_DIM;
    const float* ac = Ac + ((size_t)b * L_SEQ + j) * H_DIM;
    const float* pr = prel + (size_t)r * H_DIM;

    const int i0 = lane * 4;         // 0..252
    const int i1 = 256 + lane * 4;   // tail: valid for lane < 11
    const bool tail = (lane < 11);

    float4 h0, h1 = make_float4(0.f, 0.f, 0.f, 0.f);
    {
        float4 a = *(const float4*)(ae + i0);
        float4 c = *(const float4*)(ac + i0);
        float4 q = *(const float4*)(pr + i0);
        h0 = make_float4(a.x + c.x + q.x, a.y + c.y + q.y,
                         a.z + c.z + q.z, a.w + c.w + q.w);
        if (tail) {
            float4 at = *(const float4*)(ae + i1);
            float4 ct = *(const float4*)(ac + i1);
            float4 qt = *(const float4*)(pr + i1);
            h1 = make_float4(at.x + ct.x + qt.x, at.y + ct.y + qt.y,
                             at.z + ct.z + qt.z, at.w + ct.w + qt.w);
        }
    }

    float s  = h0.x + h0.y + h0.z + h0.w + h1.x + h1.y + h1.z + h1.w;
    float ss = h0.x*h0.x + h0.y*h0.y + h0.z*h0.z + h0.w*h0.w
             + h1.x*h1.x + h1.y*h1.y + h1.z*h1.z + h1.w*h1.w;
#pragma unroll
    for (int off = 32; off > 0; off >>= 1) {
        s  += __shfl_xor(s, off);
        ss += __shfl_xor(ss, off);
    }
    const float mu   = s * (1.f / H_DIM);
    const float var  = ss * (1.f / H_DIM) - mu * mu;
    const float rsig = rsqrtf(var + LN_EPS);

    float acc;
    {
        float4 g = *(const float4*)(ln_g + i0);
        float4 bb = *(const float4*)(ln_b + i0);
        float4 w = *(const float4*)(W2 + i0);
        float e0 = (h0.x - mu) * rsig * g.x + bb.x;
        float e1 = (h0.y - mu) * rsig * g.y + bb.y;
        float e2 = (h0.z - mu) * rsig * g.z + bb.z;
        float e3 = (h0.w - mu) * rsig * g.w + bb.w;
        e0 = e0 > 0.f ? e0 : expm1f(e0);
        e1 = e1 > 0.f ? e1 : expm1f(e1);
        e2 = e2 > 0.f ? e2 : expm1f(e2);
        e3 = e3 > 0.f ? e3 : expm1f(e3);
        acc = e0 * w.x + e1 * w.y + e2 * w.z + e3 * w.w;
        if (tail) {
            float4 gt = *(const float4*)(ln_g + i1);
            float4 bt = *(const float4*)(ln_b + i1);
            float4 wt = *(const float4*)(W2 + i1);
            float f0 = (h1.x - mu) * rsig * gt.x + bt.x;
            float f1 = (h1.y - mu) * rsig * gt.y + bt.y;
            float f2 = (h1.z - mu) * rsig * gt.z + bt.z;
            float f3 = (h1.w - mu) * rsig * gt.w + bt.w;
            f0 = f0 > 0.f ? f0 : expm1f(f0);
            f1 = f1 > 0.f ? f1 : expm1f(f1);
            f2 = f2 > 0.f ? f2 : expm1f(f2);
            f3 = f3 > 0.f ? f3 : expm1f(f3);
            acc += f0 * wt.x + f1 * wt.y + f2 * wt.z + f3 * wt.w;
        }
    }
#pragma unroll
    for (int off = 32; off > 0; off >>= 1) acc += __shfl_xor(acc, off);

    if (lane == 0) {
        out[p] = acc + b2[0];
        if (p < NC) {   // b == 0: write emo_cau_pos once
            posout[2 * (size_t)n]     = (float)(i + 1);
            posout[2 * (size_t)n + 1] = (float)(j + 1);
        }
    }
}

// ---------------------------------------------------------------------------
extern "C" void kernel_launch(void* const* d_in, const int* in_sizes, int n_in,
                              void* d_out, int out_size, void* d_ws, size_t ws_size,
                              hipStream_t stream) {
    const float* h_e     = (const float*)d_in[0];
    const float* h_c     = (const float*)d_in[1];
    const float* h_share = (const float*)d_in[2];
    // d_in[3] = mask (unused)
    const float* pos_W   = (const float*)d_in[4];
    const float* W1      = (const float*)d_in[5];
    const float* b1      = (const float*)d_in[6];
    const float* ln_g    = (const float*)d_in[7];
    const float* ln_b    = (const float*)d_in[8];
    const float* W2      = (const float*)d_in[9];
    const float* b2      = (const float*)d_in[10];

    float* ws   = (float*)d_ws;
    float* prel = ws + PREL_OFF;
    float* Ae   = ws + AE_OFF;
    float* Ac   = ws + AC_OFF;

    float* out    = (float*)d_out;
    float* posout = out + BNC;

    prep_kernel<<<dim3((NREL * H_DIM + 255) / 256), 256, 0, stream>>>(
        pos_W, W1, b1, prel);

    dim3 ggrid(NB * L_SEQ / BM, (H_DIM + BN - 1) / BN, 2);  // 64 x 5 x 2
    dual_gemm<<<ggrid, 256, 0, stream>>>(h_e, h_c, h_share, W1, Ae, Ac);

    epilogue_kernel<<<(BNC + 3) / 4, 256, 0, stream>>>(
        Ae, Ac, prel, ln_g, ln_b, W2, b2, out, posout);
}

// Round 3
// 144.034 us; speedup vs baseline: 1.3634x; 1.2774x over previous
//
#include <hip/hip_runtime.h>
#include <hip/hip_bf16.h>
#include <math.h>

// Problem constants
#define L_SEQ   1024
#define NB      8
#define H_DIM   300
#define KWIN    5
#define NREL    11          // 2K+1
#define PDIM    50
#define NC      11234       // band pair count for L=1024, K=5
#define BNC     (NB*NC)     // 89872
#define LN_EPS  1e-5f

#define KPAD    320         // K padded (zeros in 300..319), 10 x BK=32
#define WKSTR   304         // Wb k-stride (shorts): 608 B, 16B-aligned
#define WNPAD   320         // Wb n rows padded (n0=256 tile reads rows up to 319)

// Workspace layout (float offsets)
#define PREL_OFF  0                         // 11*300 fp32 -> 3328
#define WB_OFF    3328                      // 2*320*304 shorts = 97280 floats
#define AE_OFF    (3328 + 97280)            // 8192*300 shorts = 1228800 floats
// Ac follows Ae; total = 2,558,208 floats = 9.8 MiB

typedef __attribute__((ext_vector_type(8))) short s16x8;
typedef __attribute__((ext_vector_type(4))) short s16x4;
typedef __attribute__((ext_vector_type(4))) float f32x4;

// fp32 -> bf16 round-to-nearest-even
__device__ __forceinline__ short f2bf(float f) {
    unsigned u = __float_as_uint(f);
    u += 0x7fffu + ((u >> 16) & 1u);
    return (short)(u >> 16);
}
__device__ __forceinline__ float bf2f(short s) {
    return __uint_as_float(((unsigned)(unsigned short)s) << 16);
}

// ---------------------------------------------------------------------------
// n -> (i, j) for the band, row-major (i outer). Matches numpy _band_indices.
__device__ __forceinline__ void pair_from_n(int n, int& i, int& j) {
    if (n < 40) {
        if      (n < 6)  { i = 0; j = n; }
        else if (n < 13) { i = 1; j = n - 6; }
        else if (n < 21) { i = 2; j = n - 13; }
        else if (n < 30) { i = 3; j = n - 21; }
        else             { i = 4; j = n - 30; }
    } else if (n < 11194) {
        int t = n - 40;
        i = 5 + t / 11;
        j = (i - 5) + t % 11;
    } else {
        if      (n < 11204) { i = 1019; j = 1014 + (n - 11194); }
        else if (n < 11213) { i = 1020; j = 1015 + (n - 11204); }
        else if (n < 11221) { i = 1021; j = 1016 + (n - 11213); }
        else if (n < 11228) { i = 1022; j = 1017 + (n - 11221); }
        else                { i = 1023; j = 1018 + (n - 11228); }
    }
}

// ---------------------------------------------------------------------------
// Kernel 1: prep.
//  blocks 0..12   : prel[r][h] = b1[h] + sum_d W1[h][600+d]*emb11[r][d]
//  blocks 13..772 : Wb[z][n][k] = bf16(W1[n][z*300+k]) (zero-padded n>=300,k>=300)
__global__ __launch_bounds__(256) void prep_kernel(
    const float* __restrict__ pos_W, const float* __restrict__ W1,
    const float* __restrict__ b1, float* __restrict__ prel,
    short* __restrict__ Wb)
{
    if (blockIdx.x < 13) {
        __shared__ float semb[NREL * PDIM];  // 550 floats
        for (int t = threadIdx.x; t < NREL * PDIM; t += 256) {
            int r = t / PDIM, d = t % PDIM;
            float acc = 0.f;
#pragma unroll
            for (int r2 = 0; r2 < NREL; ++r2) {
                float cnt = (float)(L_SEQ - abs(r2 - KWIN));
                int dr = r - r2;
                acc += cnt * expf(-(float)(dr * dr)) * pos_W[r2 * PDIM + d];
            }
            semb[t] = acc;
        }
        __syncthreads();
        int t = blockIdx.x * 256 + threadIdx.x;
        if (t < NREL * H_DIM) {
            int r = t / H_DIM, h = t % H_DIM;
            float acc = b1[h];
            const float* wrow = W1 + (size_t)h * 650 + 600;
            const float* em = semb + r * PDIM;
#pragma unroll 10
            for (int d = 0; d < PDIM; ++d) acc += wrow[d] * em[d];
            prel[t] = acc;
        }
    } else {
        int id = (blockIdx.x - 13) * 256 + threadIdx.x;
        if (id < 2 * WNPAD * WKSTR) {
            int z = id / (WNPAD * WKSTR);
            int rem = id % (WNPAD * WKSTR);
            int n = rem / WKSTR, k = rem % WKSTR;
            float v = (n < H_DIM && k < H_DIM) ? W1[(size_t)n * 650 + z * H_DIM + k] : 0.f;
            Wb[id] = f2bf(v);
        }
    }
}

// ---------------------------------------------------------------------------
// Kernel 2: merged dual GEMM, bf16 MFMA 16x16x32, bf16 C output.
//   Ae[m][n] = sum_k (h_e[m][k]+h_share[m][k]) * W1[n][k]
//   Ac[m][n] = sum_k (h_c[m][k]+h_share[m][k]) * W1[n][300+k]
// M=8192, N=300 (5 tiles of 64), K=320 (10 steps of 32, zero tail).
// BM=32, BN=64; 4 waves: wave = (z, n-half); each wave 32x32 = 2x2 frags.
// Grid 256 x 5 = 1280 blocks -> 5 blocks/CU, 20 waves/CU.
#define BM 32
#define BN 64
#define BK 32

__global__ __launch_bounds__(256) void gemm_fused(
    const float* __restrict__ h_e, const float* __restrict__ h_c,
    const float* __restrict__ h_share, const short* __restrict__ Wb,
    short* __restrict__ Ae, short* __restrict__ Ac)
{
    __shared__ __align__(16) short As[2 * BM * BK];   // [z][row][k] 4 KB
    __shared__ __align__(16) short Bs[2 * BN * BK];   // [z][row][k] 8 KB

    const int m0 = blockIdx.x * BM;
    const int n0 = blockIdx.y * BN;

    const int tid  = threadIdx.x;
    const int wave = tid >> 6;
    const int lane = tid & 63;
    const int wz   = wave & 1;          // 0: Ae, 1: Ac
    const int wnh  = wave >> 1;         // n-half (0/1)
    const int fr   = lane & 15;
    const int fq   = lane >> 4;

    // A staging map: row = tid>>3 (0..31), kc = (tid&7)*4
    const int arow = tid >> 3;
    const int akc  = (tid & 7) * 4;
    const size_t abase = (size_t)(m0 + arow) * H_DIM;

    // B staging chunks: c = tid and tid+256 over 512 16B-chunks
    //   c -> z = c>>8, row = (c>>2)&63, kc = (c&3)*8 ; LDS offset = c*8 shorts
    f32x4 acc[2][2] = {};

    for (int k0 = 0; k0 < KPAD; k0 += BK) {
        // ---- stage A (both z): bf16(h_e+h_share), bf16(h_c+h_share)
        {
            int k = k0 + akc;
            float4 e4 = make_float4(0.f,0.f,0.f,0.f), c4 = e4;
            if (k < H_DIM) {
                float4 he = *(const float4*)(h_e + abase + k);
                float4 hc = *(const float4*)(h_c + abase + k);
                float4 hs = *(const float4*)(h_share + abase + k);
                e4 = make_float4(he.x+hs.x, he.y+hs.y, he.z+hs.z, he.w+hs.w);
                c4 = make_float4(hc.x+hs.x, hc.y+hs.y, hc.z+hs.z, hc.w+hs.w);
            }
            s16x4 ve = { f2bf(e4.x), f2bf(e4.y), f2bf(e4.z), f2bf(e4.w) };
            s16x4 vc = { f2bf(c4.x), f2bf(c4.y), f2bf(c4.z), f2bf(c4.w) };
            *(s16x4*)&As[arow * BK + akc]            = ve;
            *(s16x4*)&As[BM * BK + arow * BK + akc]  = vc;
        }
        // ---- stage B: copy bf16 Wb tile (2 x 16B chunks per thread)
#pragma unroll
        for (int p = 0; p < 2; ++p) {
            int c = tid + p * 256;
            int bz = c >> 8, brow = (c >> 2) & 63, bkc = (c & 3) * 8;
            const short* gp = Wb + ((size_t)bz * WNPAD + n0 + brow) * WKSTR + k0 + bkc;
            *(s16x8*)&Bs[c * 8] = *(const s16x8*)gp;
        }
        __syncthreads();

        // ---- MFMA: wave (wz, wnh): 2x2 frags of 16x16x32
        const short* as = As + wz * (BM * BK);
        const short* bs = Bs + wz * (BN * BK);
        s16x8 af0 = *(const s16x8*)&as[(fr)      * BK + fq * 8];
        s16x8 af1 = *(const s16x8*)&as[(16 + fr) * BK + fq * 8];
        s16x8 bf0 = *(const s16x8*)&bs[(wnh * 32 + fr)      * BK + fq * 8];
        s16x8 bf1 = *(const s16x8*)&bs[(wnh * 32 + 16 + fr) * BK + fq * 8];
        acc[0][0] = __builtin_amdgcn_mfma_f32_16x16x32_bf16(af0, bf0, acc[0][0], 0, 0, 0);
        acc[0][1] = __builtin_amdgcn_mfma_f32_16x16x32_bf16(af0, bf1, acc[0][1], 0, 0, 0);
        acc[1][0] = __builtin_amdgcn_mfma_f32_16x16x32_bf16(af1, bf0, acc[1][0], 0, 0, 0);
        acc[1][1] = __builtin_amdgcn_mfma_f32_16x16x32_bf16(af1, bf1, acc[1][1], 0, 0, 0);
        __syncthreads();
    }

    // ---- store bf16. C/D layout: col = lane&15, row = fq*4 + reg
    short* C = wz ? Ac : Ae;
#pragma unroll
    for (int nt = 0; nt < 2; ++nt) {
        const int col = n0 + wnh * 32 + nt * 16 + fr;
        if (col < H_DIM) {
#pragma unroll
            for (int mt = 0; mt < 2; ++mt) {
                const int rbase = m0 + mt * 16 + fq * 4;
#pragma unroll
                for (int r2 = 0; r2 < 4; ++r2)
                    C[(size_t)(rbase + r2) * H_DIM + col] = f2bf(acc[mt][nt][r2]);
            }
        }
    }
}

// ---------------------------------------------------------------------------
// Kernel 3: epilogue. One wave per (b, n) pair; bf16 Ae/Ac rows.
__global__ __launch_bounds__(256) void epilogue_kernel(
    const short* __restrict__ Ae, const short* __restrict__ Ac,
    const float* __restrict__ prel,
    const float* __restrict__ ln_g, const float* __restrict__ ln_b,
    const float* __restrict__ W2, const float* __restrict__ b2,
    float* __restrict__ out, float* __restrict__ posout)
{
    const int wave = threadIdx.x >> 6;
    const int lane = threadIdx.x & 63;
    const unsigned p = blockIdx.x * 4 + wave;   // pair id
    if (p >= BNC) return;

    const unsigned b = p / NC;
    const int n = (int)(p % NC);
    int i, j;
    pair_from_n(n, i, j);
    const int r = j - i + KWIN;

    const short* ae = Ae + ((size_t)b * L_SEQ + i) * H_DIM;
    const short* ac = Ac + ((size_t)b * L_SEQ + j) * H_DIM;
    const float* pr = prel + (size_t)r * H_DIM;

    const int i0 = lane * 4;         // 0..252
    const int i1 = 256 + lane * 4;   // tail: lanes 0..10
    const bool tail = (lane < 11);

    float4 h0, h1 = make_float4(0.f, 0.f, 0.f, 0.f);
    {
        s16x4 a = *(const s16x4*)(ae + i0);
        s16x4 c = *(const s16x4*)(ac + i0);
        float4 q = *(const float4*)(pr + i0);
        h0 = make_float4(bf2f(a.x) + bf2f(c.x) + q.x,
                         bf2f(a.y) + bf2f(c.y) + q.y,
                         bf2f(a.z) + bf2f(c.z) + q.z,
                         bf2f(a.w) + bf2f(c.w) + q.w);
        if (tail) {
            s16x4 at = *(const s16x4*)(ae + i1);
            s16x4 ct = *(const s16x4*)(ac + i1);
            float4 qt = *(const float4*)(pr + i1);
            h1 = make_float4(bf2f(at.x) + bf2f(ct.x) + qt.x,
                             bf2f(at.y) + bf2f(ct.y) + qt.y,
                             bf2f(at.z) + bf2f(ct.z) + qt.z,
                             bf2f(at.w) + bf2f(ct.w) + qt.w);
        }
    }

    float s  = h0.x + h0.y + h0.z + h0.w + h1.x + h1.y + h1.z + h1.w;
    float ss = h0.x*h0.x + h0.y*h0.y + h0.z*h0.z + h0.w*h0.w
             + h1.x*h1.x + h1.y*h1.y + h1.z*h1.z + h1.w*h1.w;
#pragma unroll
    for (int off = 32; off > 0; off >>= 1) {
        s  += __shfl_xor(s, off);
        ss += __shfl_xor(ss, off);
    }
    const float mu   = s * (1.f / H_DIM);
    const float var  = ss * (1.f / H_DIM) - mu * mu;
    const float rsig = rsqrtf(var + LN_EPS);

    float acc;
    {
        float4 g = *(const float4*)(ln_g + i0);
        float4 bb = *(const float4*)(ln_b + i0);
        float4 w = *(const float4*)(W2 + i0);
        float e0 = (h0.x - mu) * rsig * g.x + bb.x;
        float e1 = (h0.y - mu) * rsig * g.y + bb.y;
        float e2 = (h0.z - mu) * rsig * g.z + bb.z;
        float e3 = (h0.w - mu) * rsig * g.w + bb.w;
        e0 = e0 > 0.f ? e0 : __expf(e0) - 1.f;
        e1 = e1 > 0.f ? e1 : __expf(e1) - 1.f;
        e2 = e2 > 0.f ? e2 : __expf(e2) - 1.f;
        e3 = e3 > 0.f ? e3 : __expf(e3) - 1.f;
        acc = e0 * w.x + e1 * w.y + e2 * w.z + e3 * w.w;
        if (tail) {
            float4 gt = *(const float4*)(ln_g + i1);
            float4 bt = *(const float4*)(ln_b + i1);
            float4 wt = *(const float4*)(W2 + i1);
            float f0 = (h1.x - mu) * rsig * gt.x + bt.x;
            float f1 = (h1.y - mu) * rsig * gt.y + bt.y;
            float f2 = (h1.z - mu) * rsig * gt.z + bt.z;
            float f3 = (h1.w - mu) * rsig * gt.w + bt.w;
            f0 = f0 > 0.f ? f0 : __expf(f0) - 1.f;
            f1 = f1 > 0.f ? f1 : __expf(f1) - 1.f;
            f2 = f2 > 0.f ? f2 : __expf(f2) - 1.f;
            f3 = f3 > 0.f ? f3 : __expf(f3) - 1.f;
            acc += f0 * wt.x + f1 * wt.y + f2 * wt.z + f3 * wt.w;
        }
    }
#pragma unroll
    for (int off = 32; off > 0; off >>= 1) acc += __shfl_xor(acc, off);

    if (lane == 0) {
        out[p] = acc + b2[0];
        if (p < NC) {
            posout[2 * (size_t)n]     = (float)(i + 1);
            posout[2 * (size_t)n + 1] = (float)(j + 1);
        }
    }
}

// ---------------------------------------------------------------------------
extern "C" void kernel_launch(void* const* d_in, const int* in_sizes, int n_in,
                              void* d_out, int out_size, void* d_ws, size_t ws_size,
                              hipStream_t stream) {
    const float* h_e     = (const float*)d_in[0];
    const float* h_c     = (const float*)d_in[1];
    const float* h_share = (const float*)d_in[2];
    // d_in[3] = mask (unused)
    const float* pos_W   = (const float*)d_in[4];
    const float* W1      = (const float*)d_in[5];
    const float* b1      = (const float*)d_in[6];
    const float* ln_g    = (const float*)d_in[7];
    const float* ln_b    = (const float*)d_in[8];
    const float* W2      = (const float*)d_in[9];
    const float* b2      = (const float*)d_in[10];

    float* ws   = (float*)d_ws;
    float* prel = ws + PREL_OFF;
    short* Wb   = (short*)(ws + WB_OFF);
    short* Ae   = (short*)(ws + AE_OFF);
    short* Ac   = Ae + (size_t)NB * L_SEQ * H_DIM;

    float* out    = (float*)d_out;
    float* posout = out + BNC;

    prep_kernel<<<13 + (2 * WNPAD * WKSTR + 255) / 256, 256, 0, stream>>>(
        pos_W, W1, b1, prel, Wb);

    dim3 ggrid(NB * L_SEQ / BM, (H_DIM + BN - 1) / BN);   // 256 x 5
    gemm_fused<<<ggrid, 256, 0, stream>>>(h_e, h_c, h_share, Wb, Ae, Ac);

    epilogue_kernel<<<(BNC + 3) / 4, 256, 0, stream>>>(
        Ae, Ac, prel, ln_g, ln_b, W2, b2, out, posout);
}